// Round 5
// baseline (649.350 us; speedup 1.0000x reference)
//
#include <hip/hip_runtime.h>

// DeepAttention: h = tanh([attn@ctx, x] @ Wout^T-ish), attn = softmax(mask(w . relu(ctx@W^T)))
// R5: k_logits v3 — direct HBM->register A-fragments (no ctx LDS, no loop barriers),
// W fragment-packed in LDS (read-only), 2 blocks/CU / 4 waves/SIMD. f32x4 gather in k_wpartial.

#define BB 128
#define SS 8192
#define DD 128
#define WCH 16             // S-chunks for the weighted gather
#define WLEN (SS / WCH)    // 512 positions per gather block

typedef float f32x4_t __attribute__((ext_vector_type(4)));
typedef short bf16x8_t __attribute__((ext_vector_type(8)));
typedef unsigned short u16x8_t __attribute__((ext_vector_type(8)));
typedef unsigned int u32x4_t __attribute__((ext_vector_type(4)));

__device__ __forceinline__ unsigned short f2bf(float x) {
  unsigned u = __builtin_bit_cast(unsigned, x);
  unsigned r = (u + 0x7FFFu + ((u >> 16) & 1u)) >> 16;
  return (unsigned short)r;
}
__device__ __forceinline__ float bf2f(unsigned short h) {
  unsigned u = ((unsigned)h) << 16;
  return __builtin_bit_cast(float, u);
}
__device__ __forceinline__ unsigned cvt2bf(float a, float b) {
  return (unsigned)f2bf(a) | ((unsigned)f2bf(b) << 16);      // low16 = a, high16 = b
}

// ---- K0: detect mask storage format (0 = int32, 1 = uint8, 2 = float32) ----
__global__ void k_detect(const unsigned int* __restrict__ mw, unsigned int* __restrict__ flag) {
  int i = blockIdx.x * 256 + threadIdx.x;   // 1024 blocks -> 262144 words = 1 MB
  unsigned v = mw[i];
  unsigned f = 0;
  if (v == 0x3F800000u) f = 2u;             // f32 1.0 pattern
  else if (v > 1u) f = 1u;                  // packed uint8 bools
  if (f) atomicOr(flag, f);
}

// ---- K1a: split W into bf16 hi/lo (W accurate to ~16 mantissa bits) ----
__global__ void k_splitW(const float* __restrict__ Wg, unsigned short* __restrict__ Whi,
                         unsigned short* __restrict__ Wlo) {
  int i = blockIdx.x * 256 + threadIdx.x;   // 64 blocks -> 16384
  float x = Wg[i];
  unsigned short h = f2bf(x);
  Whi[i] = h;
  Wlo[i] = f2bf(x - bf2f(h));
}

// ---- K1b: w[b,e] = relu(x@W^T)[b,e] * V[e], fp32 exact ----
__global__ void k_w(const float* __restrict__ inp, const float* __restrict__ Wg,
                    const float* __restrict__ Vg, float* __restrict__ wv) {
  int b = blockIdx.x, e = threadIdx.x;
  __shared__ float xin[DD];
  xin[e] = inp[b * DD + e];
  __syncthreads();
  const float* wr = Wg + e * DD;
  float s = 0.f;
#pragma unroll 8
  for (int d = 0; d < DD; ++d) s += xin[d] * wr[d];
  wv[b * DD + e] = fmaxf(s, 0.f) * Vg[e];
}

// ---- K2 v3: logits[b,s] = sum_e w[b,e]*relu(sum_d ctx[b,s,d]*W[e,d]) ----
// A-fragments loaded straight from HBM (lane-exact), W hi/lo fragment-packed in LDS.
// No barriers in the main loop; grid (4, BB), 512 threads, 2 blocks/CU.
__launch_bounds__(512, 4)
__global__ void k_logits(const float* __restrict__ ctx, const unsigned short* __restrict__ Whi,
                         const unsigned short* __restrict__ Wlo, const float* __restrict__ wv,
                         float* __restrict__ logits) {
  __shared__ unsigned short WPKH[16384];     // 32 KB: W-hi, fragment-packed
  __shared__ unsigned short WPKL[16384];     // 32 KB: W-lo
  __shared__ float wl[DD];

  const int tid = threadIdx.x;
  const int b = blockIdx.y;
  const int slice = blockIdx.x;              // 0..3, 2048 rows each

  // Stage W hi/lo into packed-fragment layout. Packed unit p (16B) = frag p>>6, lane p&63.
#pragma unroll
  for (int jj = 0; jj < 4; ++jj) {
    int p = tid + jj * 512;                  // 2048 units per array
    int frag = p >> 6;                       // et*4 + ks
    int li = p & 63;
    int et = frag >> 2, ks = frag & 3;
    int lg2 = li >> 4, lr2 = li & 15;
    int src = (et * 16 + lr2) * DD + ks * 32 + lg2 * 8;
    *(u16x8_t*)(&WPKH[p * 8]) = *(const u16x8_t*)(&Whi[src]);
    *(u16x8_t*)(&WPKL[p * 8]) = *(const u16x8_t*)(&Wlo[src]);
  }
  if (tid < DD) wl[tid] = wv[b * DD + tid];
  __syncthreads();

  const int wave = tid >> 6;
  const int lane = tid & 63;
  const int lr = lane & 15;
  const int lg = lane >> 4;

  float wfreg[8];
#pragma unroll
  for (int et = 0; et < 8; ++et) wfreg[et] = wl[et * 16 + lr];

  // wave owns 256 contiguous rows; 8 groups of 32 rows (2 row-tiles of 16)
  const long rowb0 = (long)b * SS + (long)slice * 2048 + (long)wave * 256;

  for (int g = 0; g < 8; ++g) {
    const long grow = rowb0 + g * 32;
    // ---- load A-fragments straight from HBM, convert f32 -> bf16 in-register ----
    bf16x8_t a[2][4];
#pragma unroll
    for (int rt = 0; rt < 2; ++rt) {
      const float* rp = ctx + (grow + rt * 16 + lr) * (long)DD + lg * 8;
#pragma unroll
      for (int ks = 0; ks < 4; ++ks) {
        f32x4_t x0 = *(const f32x4_t*)(rp + ks * 32);
        f32x4_t x1 = *(const f32x4_t*)(rp + ks * 32 + 4);
        u32x4_t hh;
        hh[0] = cvt2bf(x0[0], x0[1]);
        hh[1] = cvt2bf(x0[2], x0[3]);
        hh[2] = cvt2bf(x1[0], x1[1]);
        hh[3] = cvt2bf(x1[2], x1[3]);
        a[rt][ks] = __builtin_bit_cast(bf16x8_t, hh);
      }
    }
    // ---- compute: 8 et-tiles of W, 2 row-tiles, hi+lo splits ----
    float part[2][4] = {{0.f, 0.f, 0.f, 0.f}, {0.f, 0.f, 0.f, 0.f}};
#pragma unroll
    for (int et = 0; et < 8; ++et) {
      bf16x8_t bh[4], bl[4];
#pragma unroll
      for (int ks = 0; ks < 4; ++ks) {
        const int pidx = ((((et << 2) | ks) << 6) | lane) << 3;
        bh[ks] = *(const bf16x8_t*)(&WPKH[pidx]);
        bl[ks] = *(const bf16x8_t*)(&WPKL[pidx]);
      }
      const float wf = wfreg[et];
#pragma unroll
      for (int rt = 0; rt < 2; ++rt) {
        f32x4_t v1 = {0.f, 0.f, 0.f, 0.f};
        f32x4_t v2 = v1;
#pragma unroll
        for (int ks = 0; ks < 4; ++ks) {
          v1 = __builtin_amdgcn_mfma_f32_16x16x32_bf16(a[rt][ks], bh[ks], v1, 0, 0, 0);
          v2 = __builtin_amdgcn_mfma_f32_16x16x32_bf16(a[rt][ks], bl[ks], v2, 0, 0, 0);
        }
#pragma unroll
        for (int i = 0; i < 4; ++i)
          part[rt][i] += wf * fmaxf(v1[i] + v2[i], 0.f);
      }
    }
    // ---- reduce over e (16 lanes share a row), store ----
#pragma unroll
    for (int rt = 0; rt < 2; ++rt) {
#pragma unroll
      for (int m = 1; m < 16; m <<= 1) {
        part[rt][0] += __shfl_xor(part[rt][0], m, 64);
        part[rt][1] += __shfl_xor(part[rt][1], m, 64);
        part[rt][2] += __shfl_xor(part[rt][2], m, 64);
        part[rt][3] += __shfl_xor(part[rt][3], m, 64);
      }
    }
    if (lr == 0) {                            // C row = 4*lg + i
      long so = grow + lg * 4;
      logits[so + 0]  = part[0][0];
      logits[so + 1]  = part[0][1];
      logits[so + 2]  = part[0][2];
      logits[so + 3]  = part[0][3];
      logits[so + 16] = part[1][0];
      logits[so + 17] = part[1][1];
      logits[so + 18] = part[1][2];
      logits[so + 19] = part[1][3];
    }
  }
}

// ---- K3: masked softmax over S per batch, in place over logits ----
__global__ void k_softmax(const float* __restrict__ logits, const void* __restrict__ mask,
                          const unsigned int* __restrict__ flag, float* __restrict__ attn) {
  const int b = blockIdx.x;
  const int tid = threadIdx.x;                  // 256
  __shared__ float buf[SS];                     // 32 KiB
  __shared__ float red[4];
  const unsigned mode = *flag;
  const long off = (long)b * SS;
  float mx = -3.4e38f;
  for (int i = tid; i < SS; i += 256) {
    float v = logits[off + i];
    bool m;
    if (mode == 0)      m = ((const int*)mask)[off + i] != 0;
    else if (mode == 1) m = ((const unsigned char*)mask)[off + i] != 0;
    else                m = ((const float*)mask)[off + i] != 0.f;
    if (m) v = -1e12f;
    buf[i] = v;
    mx = fmaxf(mx, v);
  }
#pragma unroll
  for (int m2 = 32; m2; m2 >>= 1) mx = fmaxf(mx, __shfl_xor(mx, m2, 64));
  if ((tid & 63) == 0) red[tid >> 6] = mx;
  __syncthreads();
  mx = fmaxf(fmaxf(red[0], red[1]), fmaxf(red[2], red[3]));
  float sum = 0.f;
  for (int i = tid; i < SS; i += 256) {
    float e = expf(buf[i] - mx);
    buf[i] = e;
    sum += e;
  }
#pragma unroll
  for (int m2 = 32; m2; m2 >>= 1) sum += __shfl_xor(sum, m2, 64);
  __syncthreads();
  if ((tid & 63) == 0) red[tid >> 6] = sum;
  __syncthreads();
  float inv = 1.f / (red[0] + red[1] + red[2] + red[3]);
  for (int i = tid; i < SS; i += 256) attn[off + i] = buf[i] * inv;
}

// ---- K4: partial weighted sums. grid (B, WCH), 256 thr. wpart[b][c][d] ----
// f32x4 per lane: 32 lanes cover a row; 8 groups x 2-deep unroll = 16 rows in flight.
__global__ void k_wpartial(const float* __restrict__ attn, const float* __restrict__ ctx,
                           float* __restrict__ wpart) {
  const int b = blockIdx.x, c = blockIdx.y;
  const int tid = threadIdx.x;                  // 256
  __shared__ unsigned short slist[WLEN];
  __shared__ float plist[WLEN];
  __shared__ f32x4_t part[256];                 // 4 KB
  __shared__ unsigned cnt;
  if (tid == 0) cnt = 0;
  __syncthreads();
  const long off = (long)b * SS + (long)c * WLEN;
  for (int i = tid; i < WLEN; i += 256) {
    float p = attn[off + i];
    if (p > 1e-8f) {                            // skipped mass <= 8192*1e-8*|ctx| ~ 5e-4
      unsigned k = atomicAdd(&cnt, 1u);
      slist[k] = (unsigned short)i;
      plist[k] = p;
    }
  }
  __syncthreads();
  const int n = (int)cnt;
  const int c4 = (tid & 31) * 4;
  const int g = tid >> 5;                       // 8 row-groups
  f32x4_t a0 = {0.f, 0.f, 0.f, 0.f};
  f32x4_t a1 = a0;
  int k = g;
  for (; k + 8 < n; k += 16) {
    float p0 = plist[k], p1 = plist[k + 8];
    f32x4_t r0 = *(const f32x4_t*)(ctx + (off + slist[k])     * DD + c4);
    f32x4_t r1 = *(const f32x4_t*)(ctx + (off + slist[k + 8]) * DD + c4);
    a0[0] += p0 * r0[0]; a0[1] += p0 * r0[1]; a0[2] += p0 * r0[2]; a0[3] += p0 * r0[3];
    a1[0] += p1 * r1[0]; a1[1] += p1 * r1[1]; a1[2] += p1 * r1[2]; a1[3] += p1 * r1[3];
  }
  for (; k < n; k += 8) {
    float p0 = plist[k];
    f32x4_t r0 = *(const f32x4_t*)(ctx + (off + slist[k]) * DD + c4);
    a0[0] += p0 * r0[0]; a0[1] += p0 * r0[1]; a0[2] += p0 * r0[2]; a0[3] += p0 * r0[3];
  }
  a0[0] += a1[0]; a0[1] += a1[1]; a0[2] += a1[2]; a0[3] += a1[3];
  part[tid] = a0;
  __syncthreads();
  if (tid < 32) {
    f32x4_t s = part[tid];
#pragma unroll
    for (int gg = 1; gg < 8; ++gg) {
      f32x4_t t = part[gg * 32 + tid];
      s[0] += t[0]; s[1] += t[1]; s[2] += t[2]; s[3] += t[3];
    }
    *(f32x4_t*)(&wpart[((long)b * WCH + c) * DD + tid * 4]) = s;
  }
}

// ---- K5: reduce partials, h = tanh([weighted,x]@Wout^T) ----
__global__ void k_out(const float* __restrict__ wpart, const float* __restrict__ inp,
                      const float* __restrict__ Wout, float* __restrict__ hout) {
  const int b = blockIdx.x;
  const int tid = threadIdx.x;                  // 128
  __shared__ float wsh[DD], xin[DD];
  float acc = 0.f;
#pragma unroll
  for (int cc = 0; cc < WCH; ++cc)
    acc += wpart[((long)b * WCH + cc) * DD + tid];
  wsh[tid] = acc;
  xin[tid] = inp[b * DD + tid];
  __syncthreads();
  const float* wr = Wout + tid * (2 * DD);
  float s = 0.f;
#pragma unroll 8
  for (int f = 0; f < DD; ++f) s += wsh[f] * wr[f];
#pragma unroll 8
  for (int f = 0; f < DD; ++f) s += xin[f] * wr[DD + f];
  hout[b * DD + tid] = tanhf(s);
}

extern "C" void kernel_launch(void* const* d_in, const int* in_sizes, int n_in,
                              void* d_out, int out_size, void* d_ws, size_t ws_size,
                              hipStream_t stream) {
  const float* inp  = (const float*)d_in[0];
  const float* ctx  = (const float*)d_in[1];
  const void*  mask = d_in[2];
  const float* Wg   = (const float*)d_in[3];
  const float* Vg   = (const float*)d_in[4];
  const float* Wout = (const float*)d_in[5];

  float* out = (float*)d_out;
  float* h_out = out;                 // [B, D]
  float* attn_out = out + BB * DD;    // [B, S]  (K2 writes raw logits here, K3 normalizes in place)

  char* ws = (char*)d_ws;
  unsigned int*   flag  = (unsigned int*)ws;
  unsigned short* Whi   = (unsigned short*)(ws + 1024);
  unsigned short* Wlo   = (unsigned short*)(ws + 1024 + 32768);
  float*          wv    = (float*)(ws + 1024 + 65536);
  float*          wpart = (float*)(ws + 1024 + 65536 + 65536);   // [B][WCH][DD] = 1 MB

  (void)hipMemsetAsync(flag, 0, 4, stream);
  k_detect  <<<dim3(1024),    dim3(256), 0, stream>>>((const unsigned int*)mask, flag);
  k_splitW  <<<dim3(64),      dim3(256), 0, stream>>>(Wg, Whi, Wlo);
  k_w       <<<dim3(BB),      dim3(DD),  0, stream>>>(inp, Wg, Vg, wv);
  k_logits  <<<dim3(4, BB),   dim3(512), 0, stream>>>(ctx, Whi, Wlo, wv, attn_out);
  k_softmax <<<dim3(BB),      dim3(256), 0, stream>>>(attn_out, mask, flag, attn_out);
  k_wpartial<<<dim3(BB, WCH), dim3(256), 0, stream>>>(attn_out, ctx, wpart);
  k_out     <<<dim3(BB),      dim3(128), 0, stream>>>(wpart, inp, Wout, h_out);
}

// Round 6
// 231.941 us; speedup vs baseline: 2.7996x; 2.7996x over previous
//
#include <hip/hip_runtime.h>

// DeepAttention: h = tanh([attn@ctx, x] @ Wout^T-ish), attn = softmax(mask(w . relu(ctx@W^T)))
// R6: k_logits v3b — direct HBM->register A-fragments (no ctx LDS, no loop barriers),
// W fragment-packed in LDS. Fix R5 spill disaster: launch_bounds(512,2) (256-VGPR cap),
// v_cvt_pk_bf16_f32 for f32->bf16, unroll-1 on the group loop.

#define BB 128
#define SS 8192
#define DD 128
#define WCH 16             // S-chunks for the weighted gather
#define WLEN (SS / WCH)    // 512 positions per gather block

typedef float f32x4_t __attribute__((ext_vector_type(4)));
typedef short bf16x8_t __attribute__((ext_vector_type(8)));
typedef unsigned short u16x8_t __attribute__((ext_vector_type(8)));
typedef unsigned int u32x4_t __attribute__((ext_vector_type(4)));

__device__ __forceinline__ unsigned short f2bf(float x) {
  unsigned u = __builtin_bit_cast(unsigned, x);
  unsigned r = (u + 0x7FFFu + ((u >> 16) & 1u)) >> 16;
  return (unsigned short)r;
}
__device__ __forceinline__ float bf2f(unsigned short h) {
  unsigned u = ((unsigned)h) << 16;
  return __builtin_bit_cast(float, u);
}
// hw pack: low16 = bf16(a), high16 = bf16(b)  (RNE)
__device__ __forceinline__ unsigned cvtpk(float a, float b) {
  unsigned r;
  asm("v_cvt_pk_bf16_f32 %0, %1, %2" : "=v"(r) : "v"(a), "v"(b));
  return r;
}

// ---- K0: detect mask storage format (0 = int32, 1 = uint8, 2 = float32) ----
__global__ void k_detect(const unsigned int* __restrict__ mw, unsigned int* __restrict__ flag) {
  int i = blockIdx.x * 256 + threadIdx.x;   // 1024 blocks -> 262144 words = 1 MB
  unsigned v = mw[i];
  unsigned f = 0;
  if (v == 0x3F800000u) f = 2u;             // f32 1.0 pattern
  else if (v > 1u) f = 1u;                  // packed uint8 bools
  if (f) atomicOr(flag, f);
}

// ---- K1a: split W into bf16 hi/lo (W accurate to ~16 mantissa bits) ----
__global__ void k_splitW(const float* __restrict__ Wg, unsigned short* __restrict__ Whi,
                         unsigned short* __restrict__ Wlo) {
  int i = blockIdx.x * 256 + threadIdx.x;   // 64 blocks -> 16384
  float x = Wg[i];
  unsigned short h = f2bf(x);
  Whi[i] = h;
  Wlo[i] = f2bf(x - bf2f(h));
}

// ---- K1b: w[b,e] = relu(x@W^T)[b,e] * V[e], fp32 exact ----
__global__ void k_w(const float* __restrict__ inp, const float* __restrict__ Wg,
                    const float* __restrict__ Vg, float* __restrict__ wv) {
  int b = blockIdx.x, e = threadIdx.x;
  __shared__ float xin[DD];
  xin[e] = inp[b * DD + e];
  __syncthreads();
  const float* wr = Wg + e * DD;
  float s = 0.f;
#pragma unroll 8
  for (int d = 0; d < DD; ++d) s += xin[d] * wr[d];
  wv[b * DD + e] = fmaxf(s, 0.f) * Vg[e];
}

// ---- K2 v3b: logits[b,s] = sum_e w[b,e]*relu(sum_d ctx[b,s,d]*W[e,d]) ----
// A-fragments loaded straight from HBM (lane-exact), W hi/lo fragment-packed in LDS.
// No barriers in the main loop; grid (4, BB), 512 threads.
__launch_bounds__(512, 2)
__global__ void k_logits(const float* __restrict__ ctx, const unsigned short* __restrict__ Whi,
                         const unsigned short* __restrict__ Wlo, const float* __restrict__ wv,
                         float* __restrict__ logits) {
  __shared__ unsigned short WPKH[16384];     // 32 KB: W-hi, fragment-packed
  __shared__ unsigned short WPKL[16384];     // 32 KB: W-lo
  __shared__ float wl[DD];

  const int tid = threadIdx.x;
  const int b = blockIdx.y;
  const int slice = blockIdx.x;              // 0..3, 2048 rows each

  // Stage W hi/lo into packed-fragment layout. Packed unit p (16B) = frag p>>6, lane p&63.
#pragma unroll
  for (int jj = 0; jj < 4; ++jj) {
    int p = tid + jj * 512;                  // 2048 units per array
    int frag = p >> 6;                       // et*4 + ks
    int li = p & 63;
    int et = frag >> 2, ks = frag & 3;
    int lg2 = li >> 4, lr2 = li & 15;
    int src = (et * 16 + lr2) * DD + ks * 32 + lg2 * 8;
    *(u16x8_t*)(&WPKH[p * 8]) = *(const u16x8_t*)(&Whi[src]);
    *(u16x8_t*)(&WPKL[p * 8]) = *(const u16x8_t*)(&Wlo[src]);
  }
  if (tid < DD) wl[tid] = wv[b * DD + tid];
  __syncthreads();

  const int wave = tid >> 6;
  const int lane = tid & 63;
  const int lr = lane & 15;
  const int lg = lane >> 4;

  float wfreg[8];
#pragma unroll
  for (int et = 0; et < 8; ++et) wfreg[et] = wl[et * 16 + lr];

  // wave owns 256 contiguous rows; 8 groups of 32 rows (2 row-tiles of 16)
  const long rowb0 = (long)b * SS + (long)slice * 2048 + (long)wave * 256;

#pragma unroll 1
  for (int g = 0; g < 8; ++g) {
    const long grow = rowb0 + g * 32;
    // ---- load A-fragments straight from HBM, convert f32 -> bf16 in-register ----
    bf16x8_t a[2][4];
#pragma unroll
    for (int rt = 0; rt < 2; ++rt) {
      const float* rp = ctx + (grow + rt * 16 + lr) * (long)DD + lg * 8;
#pragma unroll
      for (int ks = 0; ks < 4; ++ks) {
        f32x4_t x0 = *(const f32x4_t*)(rp + ks * 32);
        f32x4_t x1 = *(const f32x4_t*)(rp + ks * 32 + 4);
        u32x4_t hh;
        hh[0] = cvtpk(x0[0], x0[1]);
        hh[1] = cvtpk(x0[2], x0[3]);
        hh[2] = cvtpk(x1[0], x1[1]);
        hh[3] = cvtpk(x1[2], x1[3]);
        a[rt][ks] = __builtin_bit_cast(bf16x8_t, hh);
      }
    }
    // ---- compute: 8 et-tiles of W, 2 row-tiles, hi+lo splits ----
    float part[2][4] = {{0.f, 0.f, 0.f, 0.f}, {0.f, 0.f, 0.f, 0.f}};
#pragma unroll
    for (int et = 0; et < 8; ++et) {
      bf16x8_t bh[4], bl[4];
#pragma unroll
      for (int ks = 0; ks < 4; ++ks) {
        const int pidx = ((((et << 2) | ks) << 6) | lane) << 3;
        bh[ks] = *(const bf16x8_t*)(&WPKH[pidx]);
        bl[ks] = *(const bf16x8_t*)(&WPKL[pidx]);
      }
      const float wf = wfreg[et];
#pragma unroll
      for (int rt = 0; rt < 2; ++rt) {
        f32x4_t v1 = {0.f, 0.f, 0.f, 0.f};
        f32x4_t v2 = v1;
#pragma unroll
        for (int ks = 0; ks < 4; ++ks) {
          v1 = __builtin_amdgcn_mfma_f32_16x16x32_bf16(a[rt][ks], bh[ks], v1, 0, 0, 0);
          v2 = __builtin_amdgcn_mfma_f32_16x16x32_bf16(a[rt][ks], bl[ks], v2, 0, 0, 0);
        }
#pragma unroll
        for (int i = 0; i < 4; ++i)
          part[rt][i] += wf * fmaxf(v1[i] + v2[i], 0.f);
      }
    }
    // ---- reduce over e (16 lanes share a row), store ----
#pragma unroll
    for (int rt = 0; rt < 2; ++rt) {
#pragma unroll
      for (int m = 1; m < 16; m <<= 1) {
        part[rt][0] += __shfl_xor(part[rt][0], m, 64);
        part[rt][1] += __shfl_xor(part[rt][1], m, 64);
        part[rt][2] += __shfl_xor(part[rt][2], m, 64);
        part[rt][3] += __shfl_xor(part[rt][3], m, 64);
      }
    }
    if (lr == 0) {                            // C row = 4*lg + i
      long so = grow + lg * 4;
      logits[so + 0]  = part[0][0];
      logits[so + 1]  = part[0][1];
      logits[so + 2]  = part[0][2];
      logits[so + 3]  = part[0][3];
      logits[so + 16] = part[1][0];
      logits[so + 17] = part[1][1];
      logits[so + 18] = part[1][2];
      logits[so + 19] = part[1][3];
    }
  }
}

// ---- K3: masked softmax over S per batch, in place over logits ----
__global__ void k_softmax(const float* __restrict__ logits, const void* __restrict__ mask,
                          const unsigned int* __restrict__ flag, float* __restrict__ attn) {
  const int b = blockIdx.x;
  const int tid = threadIdx.x;                  // 256
  __shared__ float buf[SS];                     // 32 KiB
  __shared__ float red[4];
  const unsigned mode = *flag;
  const long off = (long)b * SS;
  float mx = -3.4e38f;
  for (int i = tid; i < SS; i += 256) {
    float v = logits[off + i];
    bool m;
    if (mode == 0)      m = ((const int*)mask)[off + i] != 0;
    else if (mode == 1) m = ((const unsigned char*)mask)[off + i] != 0;
    else                m = ((const float*)mask)[off + i] != 0.f;
    if (m) v = -1e12f;
    buf[i] = v;
    mx = fmaxf(mx, v);
  }
#pragma unroll
  for (int m2 = 32; m2; m2 >>= 1) mx = fmaxf(mx, __shfl_xor(mx, m2, 64));
  if ((tid & 63) == 0) red[tid >> 6] = mx;
  __syncthreads();
  mx = fmaxf(fmaxf(red[0], red[1]), fmaxf(red[2], red[3]));
  float sum = 0.f;
  for (int i = tid; i < SS; i += 256) {
    float e = expf(buf[i] - mx);
    buf[i] = e;
    sum += e;
  }
#pragma unroll
  for (int m2 = 32; m2; m2 >>= 1) sum += __shfl_xor(sum, m2, 64);
  __syncthreads();
  if ((tid & 63) == 0) red[tid >> 6] = sum;
  __syncthreads();
  float inv = 1.f / (red[0] + red[1] + red[2] + red[3]);
  for (int i = tid; i < SS; i += 256) attn[off + i] = buf[i] * inv;
}

// ---- K4: partial weighted sums. grid (B, WCH), 256 thr. wpart[b][c][d] ----
// f32x4 per lane: 32 lanes cover a row; 8 groups x 2-deep unroll = 16 rows in flight.
__global__ void k_wpartial(const float* __restrict__ attn, const float* __restrict__ ctx,
                           float* __restrict__ wpart) {
  const int b = blockIdx.x, c = blockIdx.y;
  const int tid = threadIdx.x;                  // 256
  __shared__ unsigned short slist[WLEN];
  __shared__ float plist[WLEN];
  __shared__ f32x4_t part[256];                 // 4 KB
  __shared__ unsigned cnt;
  if (tid == 0) cnt = 0;
  __syncthreads();
  const long off = (long)b * SS + (long)c * WLEN;
  for (int i = tid; i < WLEN; i += 256) {
    float p = attn[off + i];
    if (p > 1e-8f) {                            // skipped mass <= 8192*1e-8*|ctx| ~ 5e-4
      unsigned k = atomicAdd(&cnt, 1u);
      slist[k] = (unsigned short)i;
      plist[k] = p;
    }
  }
  __syncthreads();
  const int n = (int)cnt;
  const int c4 = (tid & 31) * 4;
  const int g = tid >> 5;                       // 8 row-groups
  f32x4_t a0 = {0.f, 0.f, 0.f, 0.f};
  f32x4_t a1 = a0;
  int k = g;
  for (; k + 8 < n; k += 16) {
    float p0 = plist[k], p1 = plist[k + 8];
    f32x4_t r0 = *(const f32x4_t*)(ctx + (off + slist[k])     * DD + c4);
    f32x4_t r1 = *(const f32x4_t*)(ctx + (off + slist[k + 8]) * DD + c4);
    a0[0] += p0 * r0[0]; a0[1] += p0 * r0[1]; a0[2] += p0 * r0[2]; a0[3] += p0 * r0[3];
    a1[0] += p1 * r1[0]; a1[1] += p1 * r1[1]; a1[2] += p1 * r1[2]; a1[3] += p1 * r1[3];
  }
  for (; k < n; k += 8) {
    float p0 = plist[k];
    f32x4_t r0 = *(const f32x4_t*)(ctx + (off + slist[k]) * DD + c4);
    a0[0] += p0 * r0[0]; a0[1] += p0 * r0[1]; a0[2] += p0 * r0[2]; a0[3] += p0 * r0[3];
  }
  a0[0] += a1[0]; a0[1] += a1[1]; a0[2] += a1[2]; a0[3] += a1[3];
  part[tid] = a0;
  __syncthreads();
  if (tid < 32) {
    f32x4_t s = part[tid];
#pragma unroll
    for (int gg = 1; gg < 8; ++gg) {
      f32x4_t t = part[gg * 32 + tid];
      s[0] += t[0]; s[1] += t[1]; s[2] += t[2]; s[3] += t[3];
    }
    *(f32x4_t*)(&wpart[((long)b * WCH + c) * DD + tid * 4]) = s;
  }
}

// ---- K5: reduce partials, h = tanh([weighted,x]@Wout^T) ----
__global__ void k_out(const float* __restrict__ wpart, const float* __restrict__ inp,
                      const float* __restrict__ Wout, float* __restrict__ hout) {
  const int b = blockIdx.x;
  const int tid = threadIdx.x;                  // 128
  __shared__ float wsh[DD], xin[DD];
  float acc = 0.f;
#pragma unroll
  for (int cc = 0; cc < WCH; ++cc)
    acc += wpart[((long)b * WCH + cc) * DD + tid];
  wsh[tid] = acc;
  xin[tid] = inp[b * DD + tid];
  __syncthreads();
  const float* wr = Wout + tid * (2 * DD);
  float s = 0.f;
#pragma unroll 8
  for (int f = 0; f < DD; ++f) s += wsh[f] * wr[f];
#pragma unroll 8
  for (int f = 0; f < DD; ++f) s += xin[f] * wr[DD + f];
  hout[b * DD + tid] = tanhf(s);
}

extern "C" void kernel_launch(void* const* d_in, const int* in_sizes, int n_in,
                              void* d_out, int out_size, void* d_ws, size_t ws_size,
                              hipStream_t stream) {
  const float* inp  = (const float*)d_in[0];
  const float* ctx  = (const float*)d_in[1];
  const void*  mask = d_in[2];
  const float* Wg   = (const float*)d_in[3];
  const float* Vg   = (const float*)d_in[4];
  const float* Wout = (const float*)d_in[5];

  float* out = (float*)d_out;
  float* h_out = out;                 // [B, D]
  float* attn_out = out + BB * DD;    // [B, S]  (K2 writes raw logits here, K3 normalizes in place)

  char* ws = (char*)d_ws;
  unsigned int*   flag  = (unsigned int*)ws;
  unsigned short* Whi   = (unsigned short*)(ws + 1024);
  unsigned short* Wlo   = (unsigned short*)(ws + 1024 + 32768);
  float*          wv    = (float*)(ws + 1024 + 65536);
  float*          wpart = (float*)(ws + 1024 + 65536 + 65536);   // [B][WCH][DD] = 1 MB

  (void)hipMemsetAsync(flag, 0, 4, stream);
  k_detect  <<<dim3(1024),    dim3(256), 0, stream>>>((const unsigned int*)mask, flag);
  k_splitW  <<<dim3(64),      dim3(256), 0, stream>>>(Wg, Whi, Wlo);
  k_w       <<<dim3(BB),      dim3(DD),  0, stream>>>(inp, Wg, Vg, wv);
  k_logits  <<<dim3(4, BB),   dim3(512), 0, stream>>>(ctx, Whi, Wlo, wv, attn_out);
  k_softmax <<<dim3(BB),      dim3(256), 0, stream>>>(attn_out, mask, flag, attn_out);
  k_wpartial<<<dim3(BB, WCH), dim3(256), 0, stream>>>(attn_out, ctx, wpart);
  k_out     <<<dim3(BB),      dim3(128), 0, stream>>>(wpart, inp, Wout, h_out);
}